// Round 10
// baseline (639.009 us; speedup 1.0000x reference)
//
#include <hip/hip_runtime.h>
#include <hip/hip_bf16.h>

typedef __attribute__((ext_vector_type(4))) float f32x4;
typedef __bf16 bf16x8 __attribute__((ext_vector_type(8)));
typedef __bf16 bf16x4 __attribute__((ext_vector_type(4)));
typedef int int4v __attribute__((ext_vector_type(4)));

#define TOKENS 16384
#define DIM    2048

__device__ __forceinline__ void gload_lds16(const void* g, void* l) {
  __builtin_amdgcn_global_load_lds((const __attribute__((address_space(1))) void*)g,
                                   (__attribute__((address_space(3))) void*)l, 16, 0, 0);
}

// ---------------- cast fp32 -> bf16, 8 elems/thread ----------------
__global__ void cast8_kernel(const float* __restrict__ src, __bf16* __restrict__ dst, int n8) {
  int i = blockIdx.x * blockDim.x + threadIdx.x;
  if (i >= n8) return;
  const float4* s = (const float4*)src;
  float4 a = s[2 * i], b = s[2 * i + 1];
  bf16x8 o;
  o[0] = (__bf16)a.x; o[1] = (__bf16)a.y; o[2] = (__bf16)a.z; o[3] = (__bf16)a.w;
  o[4] = (__bf16)b.x; o[5] = (__bf16)b.y; o[6] = (__bf16)b.z; o[7] = (__bf16)b.w;
  ((bf16x8*)dst)[i] = o;
}

// ---------------- cast Wg into W1 interleaved rows: W1[32*(g>>4)+(g&15)] = Wg[g] ----------------
__global__ void castWg_inter_kernel(const float* __restrict__ Wg, __bf16* __restrict__ W1) {
  int i = blockIdx.x * blockDim.x + threadIdx.x;   // 524288
  int g = i >> 8, c8 = (i & 255) * 8;
  const float4* s = (const float4*)(Wg + (size_t)g * DIM + c8);
  float4 a = s[0], b = s[1];
  bf16x8 o;
  o[0] = (__bf16)a.x; o[1] = (__bf16)a.y; o[2] = (__bf16)a.z; o[3] = (__bf16)a.w;
  o[4] = (__bf16)b.x; o[5] = (__bf16)b.y; o[6] = (__bf16)b.z; o[7] = (__bf16)b.w;
  int r = 32 * (g >> 4) + (g & 15);
  *(bf16x8*)(W1 + (size_t)r * DIM + c8) = o;
}

// ---------------- hidden -> Xb (straight bf16) + XT (transposed bf16) ----------------
__global__ void __launch_bounds__(256)
transcast_kernel(const float* __restrict__ src, __bf16* __restrict__ Xb, __bf16* __restrict__ XT) {
  __shared__ __bf16 Ts[64][68];
  const int ti = blockIdx.x >> 5, di = blockIdx.x & 31;
  const int s0 = ti << 6, d0 = di << 6;
  const int t = threadIdx.x, r0 = t >> 4, c4 = t & 15;
  #pragma unroll
  for (int i = 0; i < 4; ++i) {
    int row = r0 + i * 16;
    float4 v = *(const float4*)(src + (size_t)(s0 + row) * DIM + d0 + c4 * 4);
    bf16x4 o; o[0] = (__bf16)v.x; o[1] = (__bf16)v.y; o[2] = (__bf16)v.z; o[3] = (__bf16)v.w;
    *(bf16x4*)(Xb + (size_t)(s0 + row) * DIM + d0 + c4 * 4) = o;
    Ts[row][c4 * 4 + 0] = o[0]; Ts[row][c4 * 4 + 1] = o[1];
    Ts[row][c4 * 4 + 2] = o[2]; Ts[row][c4 * 4 + 3] = o[3];
  }
  __syncthreads();
  const int d = t >> 2, sq = t & 3;
  #pragma unroll
  for (int g = 0; g < 2; ++g) {
    bf16x8 o;
    #pragma unroll
    for (int k = 0; k < 8; ++k) o[k] = Ts[sq * 16 + g * 8 + k][d];
    *(bf16x8*)(XT + (size_t)(d0 + d) * TOKENS + s0 + sq * 16 + g * 8) = o;
  }
}

// ---------------- Wq [1024 x 2048] fp32 -> WqT [2048 x 1024] bf16 ----------------
__global__ void __launch_bounds__(256)
transWq_kernel(const float* __restrict__ Wq, __bf16* __restrict__ WqT) {
  __shared__ __bf16 Ts[64][68];
  const int ti = blockIdx.x >> 5, di = blockIdx.x & 31;   // 16 x 32 tiles
  const int h0 = ti << 6, d0 = di << 6;
  const int t = threadIdx.x, r0 = t >> 4, c4 = t & 15;
  #pragma unroll
  for (int i = 0; i < 4; ++i) {
    int row = r0 + i * 16;
    float4 v = *(const float4*)(Wq + (size_t)(h0 + row) * DIM + d0 + c4 * 4);
    Ts[row][c4 * 4 + 0] = (__bf16)v.x; Ts[row][c4 * 4 + 1] = (__bf16)v.y;
    Ts[row][c4 * 4 + 2] = (__bf16)v.z; Ts[row][c4 * 4 + 3] = (__bf16)v.w;
  }
  __syncthreads();
  const int d = t >> 2, sq = t & 3;
  #pragma unroll
  for (int g = 0; g < 2; ++g) {
    bf16x8 o;
    #pragma unroll
    for (int k = 0; k < 8; ++k) o[k] = Ts[sq * 16 + g * 8 + k][d];
    *(bf16x8*)(WqT + (size_t)(d0 + d) * 1024 + h0 + sq * 16 + g * 8) = o;
  }
}

// ---------------- Weff[d, h*64+k] = sum_v Wo[d, h*64+v] * mem[h,k,v] ----------------
__global__ void weff_kernel(const float* __restrict__ Wo, const float* __restrict__ mem,
                            __bf16* __restrict__ Weff) {
  int idx = blockIdx.x * blockDim.x + threadIdx.x;  // 2048*1024
  int d = idx >> 10, hk = idx & 1023, h = hk >> 6;
  const float* wo = Wo + d * 1024 + h * 64;
  const float* mm = mem + hk * 64;
  float s = 0.f;
  #pragma unroll 8
  for (int v = 0; v < 64; ++v) s += wo[v] * mm[v];
  Weff[idx] = (__bf16)s;
}

// ============ 256x256 MFMA core, BK=64, 2-buf, 4-quadrant phases (C = A @ B^T) ================
// (verified round 9: passes, SQ_LDS_BANK_CONFLICT==0)
__device__ __forceinline__ void gemm256_core(
    const __bf16* __restrict__ A, int lda,
    const __bf16* __restrict__ B, int ldb,
    int m0, int n0, int nt, char* sm, f32x4 acc[8][4]) {

  const int tid = threadIdx.x, lane = tid & 63, wid = tid >> 6;
  const int wr = wid >> 2, wc = wid & 3;
  const int lrow = lane & 15, kc = lane >> 4, s7 = lrow & 7;

  const int rowA = (wr * 64 + lrow) * 128;
  const int rowB = (wc * 32 + lrow) * 128 + 32768;
  const int sw0 = ((0 + kc) ^ s7) << 4;
  const int sw1 = ((4 + kc) ^ s7) << 4;

  unsigned oa[2][2], ob[2][2];
  #pragma unroll
  for (int h = 0; h < 2; ++h)
    #pragma unroll
    for (int L = 0; L < 2; ++L) {
      int l = h * 1024 + L * 512 + tid;
      int rl = l >> 3;
      int c  = (l & 7) ^ (rl & 7);
      int ra = ((rl & 127) >> 6) * 128 + h * 64 + (rl & 63);
      int rb = ((rl & 127) >> 5) * 64  + h * 32 + (rl & 31);
      oa[h][L] = (unsigned)(((m0 + ra) * lda + c * 8) * 2);
      ob[h][L] = (unsigned)(((n0 + rb) * ldb + c * 8) * 2);
    }
  const char* Ab = (const char*)A;
  const char* Bb = (const char*)B;

  bf16x8 avA[4][2], avB[4][2], bvA[2][2], bvB[2][2];

#define BARX() asm volatile("s_barrier" ::: "memory")
#define VM2()  asm volatile("s_waitcnt vmcnt(2)" ::: "memory")
#define VM0()  asm volatile("s_waitcnt vmcnt(0)" ::: "memory")
#define STA(bb, h, tt) do { \
    gload_lds16(Ab + oa[h][0] + (tt) * 128, sm + (bb) * 65536 + ((h) * 1024 + tid) * 16); \
    gload_lds16(Ab + oa[h][1] + (tt) * 128, sm + (bb) * 65536 + ((h) * 1024 + 512 + tid) * 16); } while (0)
#define STB(bb, h, tt) do { \
    gload_lds16(Bb + ob[h][0] + (tt) * 128, sm + (bb) * 65536 + 32768 + ((h) * 1024 + tid) * 16); \
    gload_lds16(Bb + ob[h][1] + (tt) * 128, sm + (bb) * 65536 + 32768 + ((h) * 1024 + 512 + tid) * 16); } while (0)
#define RD_AV(dst, bb, mh) \
    _Pragma("unroll") for (int f = 0; f < 4; ++f) { \
      dst[f][0] = *(const bf16x8*)(sm + (bb) * 65536 + (mh) * 16384 + rowA + f * 2048 + sw0); \
      dst[f][1] = *(const bf16x8*)(sm + (bb) * 65536 + (mh) * 16384 + rowA + f * 2048 + sw1); }
#define RD_BV(dst, bb, nh) \
    _Pragma("unroll") for (int n = 0; n < 2; ++n) { \
      dst[n][0] = *(const bf16x8*)(sm + (bb) * 65536 + (nh) * 16384 + rowB + n * 2048 + sw0); \
      dst[n][1] = *(const bf16x8*)(sm + (bb) * 65536 + (nh) * 16384 + rowB + n * 2048 + sw1); }
#define MM(av, bv, fo, no) do { \
    __builtin_amdgcn_s_setprio(1); \
    _Pragma("unroll") for (int f = 0; f < 4; ++f) \
      _Pragma("unroll") for (int n = 0; n < 2; ++n) { \
        acc[(fo) + f][(no) + n] = __builtin_amdgcn_mfma_f32_16x16x32_bf16(av[f][0], bv[n][0], acc[(fo) + f][(no) + n], 0, 0, 0); \
        acc[(fo) + f][(no) + n] = __builtin_amdgcn_mfma_f32_16x16x32_bf16(av[f][1], bv[n][1], acc[(fo) + f][(no) + n], 0, 0, 0); } \
    __builtin_amdgcn_s_setprio(0); } while (0)

#define TILE_PH(c, d, t) do { \
    RD_AV(avA, c, 0); RD_BV(bvA, c, 0); \
    STA(d, 0, (t) + 1); \
    BARX(); \
    MM(avA, bvA, 0, 0); \
    VM2(); BARX(); \
    RD_BV(bvB, c, 1); \
    STA(d, 1, (t) + 1); \
    BARX(); \
    MM(avA, bvB, 0, 2); \
    BARX(); \
    RD_AV(avB, c, 1); \
    STB(d, 0, (t) + 1); \
    BARX(); \
    MM(avB, bvB, 4, 2); \
    BARX(); \
    STB(d, 1, (t) + 1); \
    BARX(); \
    MM(avB, bvA, 4, 0); \
    VM2(); BARX(); } while (0)

#define TILE_TAIL(c) do { \
    RD_AV(avA, c, 0); RD_BV(bvA, c, 0); \
    BARX(); \
    MM(avA, bvA, 0, 0); \
    VM0(); \
    RD_BV(bvB, c, 1); \
    MM(avA, bvB, 0, 2); \
    RD_AV(avB, c, 1); \
    MM(avB, bvB, 4, 2); \
    MM(avB, bvA, 4, 0); } while (0)

  STA(0, 0, 0); STA(0, 1, 0); STB(0, 0, 0); STB(0, 1, 0);
  VM2(); BARX();

  for (int i = 0, e = (nt - 2) >> 1; i < e; ++i) {
    const int t = i << 1;
    TILE_PH(0, 1, t);
    TILE_PH(1, 0, t + 1);
  }
  TILE_PH(0, 1, nt - 2);
  TILE_TAIL(1);
#undef TILE_PH
#undef TILE_TAIL
#undef MM
#undef RD_AV
#undef RD_BV
#undef STA
#undef STB
#undef BARX
#undef VM2
#undef VM0
}

// ---------------- W2 GEMM: W2 = Weff @ WqT^T -> write into W1 interleaved rows ----------------
__global__ void __launch_bounds__(512, 1)
w2_kernel(const __bf16* __restrict__ Weff, const __bf16* __restrict__ WqT,
          __bf16* __restrict__ W1) {
  __shared__ __attribute__((aligned(16))) char smem[131072];
  const int bm = blockIdx.x >> 3, bn = blockIdx.x & 7;
  const int m0 = bm * 256, n0 = bn * 256;
  f32x4 acc[8][4] = {};
  gemm256_core(Weff, 1024, WqT, 1024, m0, n0, 16, smem, acc);

  const int tid = threadIdx.x, wid = tid >> 6, lane = tid & 63;
  const int wr = wid >> 2, wc = wid & 3;
  const int crow = (lane >> 4) << 2, ccol = lane & 15;
  #pragma unroll
  for (int f = 0; f < 8; ++f) {
    int base16 = (m0 + wr * 128) >> 4;           // i>>4 for this frag
    #pragma unroll
    for (int n = 0; n < 4; ++n) {
      int col = n0 + wc * 64 + n * 16 + ccol;
      #pragma unroll
      for (int j = 0; j < 4; ++j) {
        int r = 32 * (base16 + f) + 16 + crow + j;   // interleaved W1 row (readout slot)
        W1[(size_t)r * DIM + col] = (__bf16)acc[f][n][j];
      }
    }
  }
}

// ---------------- G GEMM: Gpart[ks] = (XT+ks*4096) @ (XT+ks*4096)^T  (split-K 4) ----------------
__global__ void __launch_bounds__(512, 1)
g_kernel(const __bf16* __restrict__ XT, float* __restrict__ Gpart) {
  __shared__ __attribute__((aligned(16))) char smem[131072];
  const int ks = blockIdx.x >> 6, rr = blockIdx.x & 63;
  const int bm = rr >> 3, bn = rr & 7;
  const int m0 = bm * 256, n0 = bn * 256;
  const __bf16* Xk = XT + ks * 4096;
  f32x4 acc[8][4] = {};
  gemm256_core(Xk, TOKENS, Xk, TOKENS, m0, n0, 64, smem, acc);

  float* P = Gpart + (size_t)ks * 4194304;
  const int tid = threadIdx.x, wid = tid >> 6, lane = tid & 63;
  const int wr = wid >> 2, wc = wid & 3;
  const int crow = (lane >> 4) << 2, ccol = lane & 15;
  #pragma unroll
  for (int f = 0; f < 8; ++f) {
    int row = m0 + wr * 128 + f * 16 + crow;
    #pragma unroll
    for (int n = 0; n < 4; ++n) {
      int col = n0 + wc * 64 + n * 16 + ccol;
      #pragma unroll
      for (int j = 0; j < 4; ++j)
        P[(size_t)(row + j) * DIM + col] = acc[f][n][j];
    }
  }
}

// ---------------- G reduce -> bf16 ----------------
__global__ void greduce_kernel(const float* __restrict__ Gpart, __bf16* __restrict__ Gb16) {
  int i4 = blockIdx.x * blockDim.x + threadIdx.x;   // 1048576
  float4 s = ((const float4*)Gpart)[i4];
  #pragma unroll
  for (int k = 1; k < 4; ++k) {
    float4 p = ((const float4*)(Gpart + (size_t)k * 4194304))[i4];
    s.x += p.x; s.y += p.y; s.z += p.z; s.w += p.w;
  }
  bf16x4 o; o[0] = (__bf16)s.x; o[1] = (__bf16)s.y; o[2] = (__bf16)s.z; o[3] = (__bf16)s.w;
  ((bf16x4*)Gb16)[i4] = o;
}

// ---------------- WkG GEMM: WkGpart[ks] = (Wkb+ks*512) @ (Gb16+ks*512)^T (G symmetric) --------
__global__ void __launch_bounds__(512, 1)
wkg_kernel(const __bf16* __restrict__ Wkb, const __bf16* __restrict__ Gb16,
           float* __restrict__ WkGpart) {
  __shared__ __attribute__((aligned(16))) char smem[131072];
  const int ks = blockIdx.x >> 5, rr = blockIdx.x & 31;
  const int bm = rr >> 3, bn = rr & 7;
  const int m0 = bm * 256, n0 = bn * 256;
  f32x4 acc[8][4] = {};
  gemm256_core(Wkb + ks * 512, DIM, Gb16 + ks * 512, DIM, m0, n0, 8, smem, acc);

  float* P = WkGpart + (size_t)ks * 2097152;
  const int tid = threadIdx.x, wid = tid >> 6, lane = tid & 63;
  const int wr = wid >> 2, wc = wid & 3;
  const int crow = (lane >> 4) << 2, ccol = lane & 15;
  #pragma unroll
  for (int f = 0; f < 8; ++f) {
    int row = m0 + wr * 128 + f * 16 + crow;
    #pragma unroll
    for (int n = 0; n < 4; ++n) {
      int col = n0 + wc * 64 + n * 16 + ccol;
      #pragma unroll
      for (int j = 0; j < 4; ++j)
        P[(size_t)(row + j) * DIM + col] = acc[f][n][j];
    }
  }
}

// ---------------- WkG reduce -> bf16 ----------------
__global__ void wkgreduce_kernel(const float* __restrict__ WkGpart, __bf16* __restrict__ WkG) {
  int i4 = blockIdx.x * blockDim.x + threadIdx.x;   // 524288
  float4 s = ((const float4*)WkGpart)[i4];
  #pragma unroll
  for (int k = 1; k < 4; ++k) {
    float4 p = ((const float4*)(WkGpart + (size_t)k * 2097152))[i4];
    s.x += p.x; s.y += p.y; s.z += p.z; s.w += p.w;
  }
  bf16x4 o; o[0] = (__bf16)s.x; o[1] = (__bf16)s.y; o[2] = (__bf16)s.z; o[3] = (__bf16)s.w;
  ((bf16x4*)WkG)[i4] = o;
}

// ---------------- memfinal: mem_out[h] = 0.99*mem[h] + WkG_h @ Wv_h^T  (16 blocks) ----------
__global__ void __launch_bounds__(256)
memfinal_kernel(const __bf16* __restrict__ WkG, const __bf16* __restrict__ Wvb,
                const float* __restrict__ mem, float* __restrict__ mem_out) {
  const int h = blockIdx.x;
  const int tid = threadIdx.x, lane = tid & 63, w = tid >> 6;
  const int lrow = lane & 15, kc = lane >> 4;
  const __bf16* Ah = WkG + (size_t)h * 64 * DIM;
  const __bf16* Bh = Wvb + (size_t)h * 64 * DIM;
  f32x4 acc[4] = {};
  const int arow = (w * 16 + lrow) * DIM + kc * 8;
  #pragma unroll 2
  for (int kt = 0; kt < 64; ++kt) {
    int ko = kt * 32;
    bf16x8 a = *(const bf16x8*)(Ah + arow + ko);
    #pragma unroll
    for (int n = 0; n < 4; ++n) {
      bf16x8 b = *(const bf16x8*)(Bh + (n * 16 + lrow) * DIM + kc * 8 + ko);
      acc[n] = __builtin_amdgcn_mfma_f32_16x16x32_bf16(a, b, acc[n], 0, 0, 0);
    }
  }
  const int crow = (lane >> 4) * 4, ccol = lane & 15;
  const int base = h * 4096;
  #pragma unroll
  for (int n = 0; n < 4; ++n)
    #pragma unroll
    for (int j = 0; j < 4; ++j) {
      int idx = base + (w * 16 + crow + j) * 64 + n * 16 + ccol;
      mem_out[idx] = 0.99f * mem[idx] + acc[n][j];
    }
}

// ---------------- GEMM_main: out = hidden + sigmoid(X@Wg^T) * (X@W2^T), W1 interleaved --------
__global__ void __launch_bounds__(512, 1)
gemm_main_kernel(const __bf16* __restrict__ Xb, const __bf16* __restrict__ W1,
                 const float* __restrict__ hidden, float* __restrict__ out) {
  __shared__ __attribute__((aligned(16))) char smem[131072];
  const int x = blockIdx.x & 7;        // XCD
  const int l = blockIdx.x >> 3;       // 0..127
  const int bm = x * 8 + (l & 7);      // 0..63
  const int bn = l >> 3;               // 0..15
  const int m0 = bm * 256, n0 = bn * 256;
  f32x4 acc[8][4] = {};
  gemm256_core(Xb, DIM, W1, DIM, m0, n0, 32, smem, acc);

  const int tid = threadIdx.x, wid = tid >> 6, lane = tid & 63;
  const int wr = wid >> 2, wc = wid & 3;
  const int crow = (lane >> 4) << 2, ccol = lane & 15;
  #pragma unroll
  for (int f = 0; f < 8; ++f) {
    int row = m0 + wr * 128 + f * 16 + crow;
    #pragma unroll
    for (int np = 0; np < 2; ++np) {
      int col = (n0 >> 1) + wc * 32 + np * 16 + ccol;
      #pragma unroll
      for (int j = 0; j < 4; ++j) {
        size_t idx = (size_t)(row + j) * DIM + col;
        float gv = 1.0f / (1.0f + __expf(-acc[f][2 * np][j]));
        out[idx] = hidden[idx] + gv * acc[f][2 * np + 1][j];
      }
    }
  }
}

extern "C" void kernel_launch(void* const* d_in, const int* in_sizes, int n_in,
                              void* d_out, int out_size, void* d_ws, size_t ws_size,
                              hipStream_t stream) {
  const float* hidden = (const float*)d_in[0];
  const float* memory = (const float*)d_in[1];
  const float* Wk = (const float*)d_in[2];
  const float* Wv = (const float*)d_in[3];
  const float* Wq = (const float*)d_in[4];
  const float* Wg = (const float*)d_in[5];
  const float* Wo = (const float*)d_in[6];
  float* out = (float*)d_out;
  float* mem_out = out + (size_t)TOKENS * DIM;

  char* ws = (char*)d_ws;
  __bf16* Xb   = (__bf16*)(ws);                    // 16384x2048  ( 67,108,864 B)
  __bf16* XT   = (__bf16*)(ws + 67108864);         // 2048x16384  ( 67,108,864 B)
  __bf16* W1   = (__bf16*)(ws + 134217728);        // 4096x2048   ( 16,777,216 B) interleaved
  __bf16* Wkb  = (__bf16*)(ws + 150994944);        // 1024x2048   (  4,194,304 B)
  __bf16* Wvb  = (__bf16*)(ws + 155189248);        // 1024x2048   (  4,194,304 B)
  __bf16* Weff = (__bf16*)(ws + 159383552);        // 2048x1024   (  4,194,304 B)
  __bf16* WqT  = (__bf16*)(ws + 163577856);        // 2048x1024   (  4,194,304 B)
  __bf16* Gb16 = (__bf16*)(ws + 167772160);        // 2048x2048   (  8,388,608 B)
  __bf16* WkG  = (__bf16*)(ws + 176160768);        // 1024x2048   (  4,194,304 B)
  float*  Gpart   = (float*)(ws + 180355072);      // 4x2048x2048 ( 67,108,864 B)
  float*  WkGpart = (float*)(ws + 180355072);      // 4x1024x2048 (reuses Gpart region)
  // total: 247,463,936 B  (< proven-available 264 MB)

  // casts / transposes / small precomputes
  transcast_kernel<<<8192, 256, 0, stream>>>(hidden, Xb, XT);
  castWg_inter_kernel<<<2048, 256, 0, stream>>>(Wg, W1);
  cast8_kernel<<<1024, 256, 0, stream>>>(Wk, Wkb, 262144);
  cast8_kernel<<<1024, 256, 0, stream>>>(Wv, Wvb, 262144);
  weff_kernel<<<8192, 256, 0, stream>>>(Wo, memory, Weff);
  transWq_kernel<<<512, 256, 0, stream>>>(Wq, WqT);

  // W2 = Weff @ Wq  -> interleaved into W1
  w2_kernel<<<64, 512, 0, stream>>>(Weff, WqT, W1);

  // G = X^T X (split-K 4) -> Gb16
  g_kernel<<<256, 512, 0, stream>>>(XT, Gpart);
  greduce_kernel<<<4096, 256, 0, stream>>>(Gpart, Gb16);

  // WkG = Wk @ G (split-K 4) -> WkG bf16
  wkg_kernel<<<128, 512, 0, stream>>>(Wkb, Gb16, WkGpart);
  wkgreduce_kernel<<<2048, 256, 0, stream>>>(WkGpart, WkG);

  // memory output
  memfinal_kernel<<<16, 256, 0, stream>>>(WkG, Wvb, memory, mem_out);

  // main fused GEMM -> out
  gemm_main_kernel<<<1024, 512, 0, stream>>>(Xb, W1, hidden, out);
}

// Round 14
// 597.523 us; speedup vs baseline: 1.0694x; 1.0694x over previous
//
#include <hip/hip_runtime.h>
#include <hip/hip_bf16.h>

typedef __attribute__((ext_vector_type(4))) float f32x4;
typedef __bf16 bf16x8 __attribute__((ext_vector_type(8)));
typedef __bf16 bf16x4 __attribute__((ext_vector_type(4)));
typedef int int4v __attribute__((ext_vector_type(4)));

#define TOKENS 16384
#define DIM    2048
#define NKVQ   3072   // Yb row stride (cols 0..1023 = K, 1024..2047 = V)

__device__ __forceinline__ void gload_lds16(const void* g, void* l) {
  __builtin_amdgcn_global_load_lds((const __attribute__((address_space(1))) void*)g,
                                   (__attribute__((address_space(3))) void*)l, 16, 0, 0);
}

// ---------------- cast fp32 -> bf16, 8 elems/thread ----------------
__global__ void cast8_kernel(const float* __restrict__ src, __bf16* __restrict__ dst, int n8) {
  int i = blockIdx.x * blockDim.x + threadIdx.x;
  if (i >= n8) return;
  const float4* s = (const float4*)src;
  float4 a = s[2 * i], b = s[2 * i + 1];
  bf16x8 o;
  o[0] = (__bf16)a.x; o[1] = (__bf16)a.y; o[2] = (__bf16)a.z; o[3] = (__bf16)a.w;
  o[4] = (__bf16)b.x; o[5] = (__bf16)b.y; o[6] = (__bf16)b.z; o[7] = (__bf16)b.w;
  ((bf16x8*)dst)[i] = o;
}

// ---------------- cast Wg into W1 interleaved rows: W1[32*(g>>4)+(g&15)] = Wg[g] ----------------
__global__ void castWg_inter_kernel(const float* __restrict__ Wg, __bf16* __restrict__ W1) {
  int i = blockIdx.x * blockDim.x + threadIdx.x;   // 524288
  int g = i >> 8, c8 = (i & 255) * 8;
  const float4* s = (const float4*)(Wg + (size_t)g * DIM + c8);
  float4 a = s[0], b = s[1];
  bf16x8 o;
  o[0] = (__bf16)a.x; o[1] = (__bf16)a.y; o[2] = (__bf16)a.z; o[3] = (__bf16)a.w;
  o[4] = (__bf16)b.x; o[5] = (__bf16)b.y; o[6] = (__bf16)b.z; o[7] = (__bf16)b.w;
  int r = 32 * (g >> 4) + (g & 15);
  *(bf16x8*)(W1 + (size_t)r * DIM + c8) = o;
}

// ---------------- Wq [1024 x 2048] fp32 -> WqT [2048 x 1024] bf16 ----------------
__global__ void __launch_bounds__(256)
transWq_kernel(const float* __restrict__ Wq, __bf16* __restrict__ WqT) {
  __shared__ __bf16 Ts[64][68];
  const int ti = blockIdx.x >> 5, di = blockIdx.x & 31;   // 16 x 32 tiles
  const int h0 = ti << 6, d0 = di << 6;
  const int t = threadIdx.x, r0 = t >> 4, c4 = t & 15;
  #pragma unroll
  for (int i = 0; i < 4; ++i) {
    int row = r0 + i * 16;
    float4 v = *(const float4*)(Wq + (size_t)(h0 + row) * DIM + d0 + c4 * 4);
    Ts[row][c4 * 4 + 0] = (__bf16)v.x; Ts[row][c4 * 4 + 1] = (__bf16)v.y;
    Ts[row][c4 * 4 + 2] = (__bf16)v.z; Ts[row][c4 * 4 + 3] = (__bf16)v.w;
  }
  __syncthreads();
  const int d = t >> 2, sq = t & 3;
  #pragma unroll
  for (int g = 0; g < 2; ++g) {
    bf16x8 o;
    #pragma unroll
    for (int k = 0; k < 8; ++k) o[k] = Ts[sq * 16 + g * 8 + k][d];
    *(bf16x8*)(WqT + (size_t)(d0 + d) * 1024 + h0 + sq * 16 + g * 8) = o;
  }
}

// ---------------- Weff[d, h*64+k] = sum_v Wo[d, h*64+v] * mem[h,k,v] ----------------
__global__ void weff_kernel(const float* __restrict__ Wo, const float* __restrict__ mem,
                            __bf16* __restrict__ Weff) {
  int idx = blockIdx.x * blockDim.x + threadIdx.x;  // 2048*1024
  int d = idx >> 10, hk = idx & 1023, h = hk >> 6;
  const float* wo = Wo + d * 1024 + h * 64;
  const float* mm = mem + hk * 64;
  float s = 0.f;
  #pragma unroll 8
  for (int v = 0; v < 64; ++v) s += wo[v] * mm[v];
  Weff[idx] = (__bf16)s;
}

// ================= 256x256 MFMA core, BK=32, 4-buf ring (C = A @ B^T) ========================
// EXACT round-6-benched version (4/4 replay-validated passes across rounds 4-7).
// 512 threads = 8 waves (2 wave-rows x 4 wave-cols); per-wave 128x64 out; acc[8][4] f32x4.
// LDS 128KB = 4 bufs x (A 16KB + B 16KB). Tile: 256 rows x K=32. nt = K/32 (multiple of 4).
// Swizzle (16B units): phys = u ^ ((u>>3)&7); pre-swizzled global src, swizzled reads.
__device__ __forceinline__ void gemm256_core(
    const __bf16* __restrict__ A, int lda,
    const __bf16* __restrict__ B, int ldb,
    int m0, int n0, int nt, char* sm, f32x4 acc[8][4]) {

  const int tid = threadIdx.x, lane = tid & 63, wid = tid >> 6;
  const int wr = wid >> 2, wc = wid & 3;
  const int lrow = lane & 15, kc = lane >> 4;

  int offA[8], offB[4];
  #pragma unroll
  for (int m = 0; m < 8; ++m) {
    int u = (wr * 128 + m * 16 + lrow) * 4 + kc;
    offA[m] = (u ^ ((u >> 3) & 7)) << 4;
  }
  #pragma unroll
  for (int n = 0; n < 4; ++n) {
    int u = (wc * 64 + n * 16 + lrow) * 4 + kc;
    offB[n] = ((u ^ ((u >> 3) & 7)) << 4) + 16384;
  }

  const __bf16* pSA[2]; const __bf16* pSB[2];
  #pragma unroll
  for (int s = 0; s < 2; ++s) {
    int U = s * 512 + tid;
    int u = U ^ ((U >> 3) & 7);
    pSA[s] = A + (size_t)(m0 + (u >> 2)) * lda + (u & 3) * 8;
    pSB[s] = B + (size_t)(n0 + (u >> 2)) * ldb + (u & 3) * 8;
  }

  bf16x8 bvS0[4], bvS1[4];

#define BARX() asm volatile("s_barrier" ::: "memory")
#define VM4()  asm volatile("s_waitcnt vmcnt(4)" ::: "memory")
#define VM0()  asm volatile("s_waitcnt vmcnt(0)" ::: "memory")
#define NOVM
#define NOSTAGE
#define STAGE(bb, tt) do { \
    char* sA = sm + (bb) * 32768 + tid * 16; \
    gload_lds16(pSA[0] + (tt) * 32, sA); \
    gload_lds16(pSA[1] + (tt) * 32, sA + 8192); \
    gload_lds16(pSB[0] + (tt) * 32, sA + 16384); \
    gload_lds16(pSB[1] + (tt) * 32, sA + 24576); } while (0)

#define PH(bufC, bufN, C, N, STG, WT) do { \
    const char* bC = sm + (bufC) * 32768; \
    const char* bN = sm + (bufN) * 32768; \
    bf16x8 av[8]; \
    _Pragma("unroll") for (int m = 0; m < 8; ++m) av[m] = *(const bf16x8*)(bC + offA[m]); \
    _Pragma("unroll") for (int n = 0; n < 4; ++n) bvS##N[n] = *(const bf16x8*)(bN + offB[n]); \
    STG; \
    __builtin_amdgcn_s_setprio(1); \
    _Pragma("unroll") for (int m = 0; m < 8; ++m) \
      _Pragma("unroll") for (int n = 0; n < 4; ++n) \
        acc[m][n] = __builtin_amdgcn_mfma_f32_16x16x32_bf16(av[m], bvS##C[n], acc[m][n], 0, 0, 0); \
    __builtin_amdgcn_s_setprio(0); \
    WT; BARX(); } while (0)

#define PHF(bufC, C) do { \
    const char* bC = sm + (bufC) * 32768; \
    bf16x8 av[8]; \
    _Pragma("unroll") for (int m = 0; m < 8; ++m) av[m] = *(const bf16x8*)(bC + offA[m]); \
    __builtin_amdgcn_s_setprio(1); \
    _Pragma("unroll") for (int m = 0; m < 8; ++m) \
      _Pragma("unroll") for (int n = 0; n < 4; ++n) \
        acc[m][n] = __builtin_amdgcn_mfma_f32_16x16x32_bf16(av[m], bvS##C[n], acc[m][n], 0, 0, 0); \
    __builtin_amdgcn_s_setprio(0); } while (0)

  STAGE(0, 0); STAGE(1, 1); STAGE(2, 2);
  VM4(); BARX();
  #pragma unroll
  for (int n = 0; n < 4; ++n) bvS0[n] = *(const bf16x8*)(sm + offB[n]);

  for (int i = 0, e = (nt - 4) >> 2; i < e; ++i) {
    const int t = i << 2;
    PH(0, 1, 0, 1, STAGE(3, t + 3), VM4());
    PH(1, 2, 1, 0, STAGE(0, t + 4), VM4());
    PH(2, 3, 0, 1, STAGE(1, t + 5), VM4());
    PH(3, 0, 1, 0, STAGE(2, t + 6), VM4());
  }
  PH(0, 1, 0, 1, STAGE(3, nt - 1), VM4());
  PH(1, 2, 1, 0, NOSTAGE, VM0());
  PH(2, 3, 0, 1, NOSTAGE, NOVM);
  PHF(3, 1);
#undef PH
#undef PHF
#undef STAGE
#undef BARX
#undef VM4
#undef VM0
#undef NOVM
#undef NOSTAGE
}

// ---------------- W2 GEMM: W2 = Weff @ WqT^T -> write into W1 interleaved rows ----------------
__global__ void __launch_bounds__(512, 1)
w2_kernel(const __bf16* __restrict__ Weff, const __bf16* __restrict__ WqT,
          __bf16* __restrict__ W1) {
  __shared__ __attribute__((aligned(16))) char smem[131072];
  const int bm = blockIdx.x >> 3, bn = blockIdx.x & 7;
  const int m0 = bm * 256, n0 = bn * 256;
  f32x4 acc[8][4] = {};
  gemm256_core(Weff, 1024, WqT, 1024, m0, n0, 32, smem, acc);

  const int tid = threadIdx.x, wid = tid >> 6, lane = tid & 63;
  const int wr = wid >> 2, wc = wid & 3;
  const int crow = (lane >> 4) << 2, ccol = lane & 15;
  #pragma unroll
  for (int f = 0; f < 8; ++f) {
    int base16 = (m0 + wr * 128) >> 4;
    #pragma unroll
    for (int n = 0; n < 4; ++n) {
      int col = n0 + wc * 64 + n * 16 + ccol;
      #pragma unroll
      for (int j = 0; j < 4; ++j) {
        int r = 32 * (base16 + f) + 16 + crow + j;   // interleaved W1 row (readout slot)
        W1[(size_t)r * DIM + col] = (__bf16)acc[f][n][j];
      }
    }
  }
}

// -------- GEMM_main: out = hidden + sigmoid(X@Wg^T) * (X@W2^T), W1 interleaved, N=4096 --------
__global__ void __launch_bounds__(512, 1)
gemm_main_kernel(const __bf16* __restrict__ Xb, const __bf16* __restrict__ W1,
                 const float* __restrict__ hidden, float* __restrict__ out) {
  __shared__ __attribute__((aligned(16))) char smem[131072];
  const int x = blockIdx.x & 7;        // XCD
  const int l = blockIdx.x >> 3;       // 0..127
  const int bm = x * 8 + (l & 7);      // 0..63
  const int bn = l >> 3;               // 0..15
  const int m0 = bm * 256, n0 = bn * 256;
  f32x4 acc[8][4] = {};
  gemm256_core(Xb, DIM, W1, DIM, m0, n0, 64, smem, acc);

  const int tid = threadIdx.x, wid = tid >> 6, lane = tid & 63;
  const int wr = wid >> 2, wc = wid & 3;
  const int crow = (lane >> 4) << 2, ccol = lane & 15;
  #pragma unroll
  for (int f = 0; f < 8; ++f) {
    int row = m0 + wr * 128 + f * 16 + crow;
    #pragma unroll
    for (int np = 0; np < 2; ++np) {
      int col = (n0 >> 1) + wc * 32 + np * 16 + ccol;
      #pragma unroll
      for (int j = 0; j < 4; ++j) {
        size_t idx = (size_t)(row + j) * DIM + col;
        float gv = 1.0f / (1.0f + __expf(-acc[f][2 * np][j]));
        out[idx] = hidden[idx] + gv * acc[f][2 * np + 1][j];
      }
    }
  }
}

// ------------- GEMM_kv: Yb[:, 0..2047] = X @ [Wk;Wv]^T  (Yb stride NKVQ=3072) ----------------
__global__ void __launch_bounds__(512, 1)
gemm_kv_kernel(const __bf16* __restrict__ Xb, const __bf16* __restrict__ Wkv,
               __bf16* __restrict__ Yb) {
  __shared__ __attribute__((aligned(16))) char smem[131072];
  const int x = blockIdx.x & 7;        // XCD
  const int l = blockIdx.x >> 3;       // 0..63
  const int bm = x * 8 + (l & 7);      // 0..63
  const int bn = l >> 3;               // 0..7
  const int m0 = bm * 256, n0 = bn * 256;
  f32x4 acc[8][4] = {};
  gemm256_core(Xb, DIM, Wkv, DIM, m0, n0, 64, smem, acc);

  // epilogue: acc -> LDS (bf16, swizzled 16B slots) -> wide NT stores (round-6 proven pattern)
  __syncthreads();
  const int tid = threadIdx.x, wid = tid >> 6, lane = tid & 63;
  const int wr = wid >> 2, wc = wid & 3;
  const int crow = (lane >> 4) << 2, ccol = lane & 15;
  #pragma unroll
  for (int f = 0; f < 8; ++f)
    #pragma unroll
    for (int n = 0; n < 4; ++n)
      #pragma unroll
      for (int j = 0; j < 4; ++j) {
        int r = wr * 128 + f * 16 + crow + j;
        int c = wc * 64 + n * 16 + ccol;
        *(__bf16*)(smem + r * 512 + ((c * 2) ^ ((r & 7) << 4))) = (__bf16)acc[f][n][j];
      }
  __syncthreads();
  const int rsub = tid >> 5, ch = tid & 31;
  #pragma unroll
  for (int p = 0; p < 16; ++p) {
    int r = p * 16 + rsub;
    bf16x8 v = *(const bf16x8*)(smem + r * 512 + ((ch * 16) ^ ((r & 7) << 4)));
    __builtin_nontemporal_store(__builtin_bit_cast(int4v, v),
        (int4v*)(Yb + (size_t)(m0 + r) * NKVQ + n0 + ch * 8));
  }
}

// ---------------- memory update partials (round-9 EXACT, NKVQ stride) ----------------
__global__ void __launch_bounds__(256)
mem_update_kernel(const __bf16* __restrict__ Y, float* __restrict__ part) {
  const int h = blockIdx.x & 15, sp = blockIdx.x >> 4;
  __shared__ __attribute__((aligned(16))) __bf16 KT[64 * 32];
  __shared__ __attribute__((aligned(16))) __bf16 VT[64 * 32];
  const int tid = threadIdx.x, wid = tid >> 6, lane = tid & 63;
  const int lrow = lane & 15, lk = (lane >> 4) * 8;
  const __bf16* Kbase = Y + (size_t)sp * 1024 * NKVQ + h * 64;
  const __bf16* Vbase = Kbase + 1024;
  f32x4 acc[4] = {};
  const int t = tid >> 3, c8 = (tid & 7) * 8;
  for (int t0 = 0; t0 < 1024; t0 += 32) {
    __syncthreads();
    bf16x8 kv = *(const bf16x8*)(Kbase + (size_t)(t0 + t) * NKVQ + c8);
    bf16x8 vv = *(const bf16x8*)(Vbase + (size_t)(t0 + t) * NKVQ + c8);
    #pragma unroll
    for (int j = 0; j < 8; ++j) {
      KT[(c8 + j) * 32 + t] = kv[j];
      VT[(c8 + j) * 32 + t] = vv[j];
    }
    __syncthreads();
    bf16x8 af = *(const bf16x8*)(KT + (wid * 16 + lrow) * 32 + lk);
    #pragma unroll
    for (int n = 0; n < 4; ++n) {
      bf16x8 bf_ = *(const bf16x8*)(VT + (n * 16 + lrow) * 32 + lk);
      acc[n] = __builtin_amdgcn_mfma_f32_16x16x32_bf16(af, bf_, acc[n], 0, 0, 0);
    }
  }
  float* pp = part + ((size_t)sp * 16 + h) * 4096;
  const int crow = wid * 16 + (lane >> 4) * 4, ccol = lane & 15;
  #pragma unroll
  for (int n = 0; n < 4; ++n)
    #pragma unroll
    for (int r = 0; r < 4; ++r)
      pp[(crow + r) * 64 + n * 16 + ccol] = acc[n][r];
}

// ---------------- memory reduce: out = 0.99*mem + sum_sp part ----------------
__global__ void mem_reduce_kernel(const float* __restrict__ part, const float* __restrict__ mem,
                                  float* __restrict__ out) {
  int i = blockIdx.x * blockDim.x + threadIdx.x;
  float s = 0.99f * mem[i];
  #pragma unroll
  for (int sp = 0; sp < 16; ++sp) s += part[sp * 65536 + i];
  out[i] = s;
}

extern "C" void kernel_launch(void* const* d_in, const int* in_sizes, int n_in,
                              void* d_out, int out_size, void* d_ws, size_t ws_size,
                              hipStream_t stream) {
  const float* hidden = (const float*)d_in[0];
  const float* memory = (const float*)d_in[1];
  const float* Wk = (const float*)d_in[2];
  const float* Wv = (const float*)d_in[3];
  const float* Wq = (const float*)d_in[4];
  const float* Wg = (const float*)d_in[5];
  const float* Wo = (const float*)d_in[6];
  float* out = (float*)d_out;
  float* mem_out = out + (size_t)TOKENS * DIM;

  char* ws = (char*)d_ws;
  __bf16* Xb   = (__bf16*)(ws);                    // 16384x2048  ( 67,108,864 B)
  __bf16* W1   = (__bf16*)(ws + 67108864);         // 4096x2048   ( 16,777,216 B) interleaved
  __bf16* Wkv  = (__bf16*)(ws + 83886080);         // 2048x2048   (  8,388,608 B)
  __bf16* Weff = (__bf16*)(ws + 92274688);         // 2048x1024   (  4,194,304 B)
  __bf16* WqT  = (__bf16*)(ws + 96468992);         // 2048x1024   (  4,194,304 B)
  __bf16* Yb   = (__bf16*)(ws + 100663296);        // 16384x3072  (100,663,296 B)
  float*  part = (float*)(ws + 201326592);         // 16x16x64x64 (  4,194,304 B)
  // total 205,520,896 B

  cast8_kernel<<<16384, 256, 0, stream>>>(hidden, Xb, 4194304);
  castWg_inter_kernel<<<2048, 256, 0, stream>>>(Wg, W1);
  cast8_kernel<<<1024, 256, 0, stream>>>(Wk, Wkv, 262144);
  cast8_kernel<<<1024, 256, 0, stream>>>(Wv, Wkv + 2097152, 262144);
  weff_kernel<<<8192, 256, 0, stream>>>(Wo, memory, Weff);
  transWq_kernel<<<512, 256, 0, stream>>>(Wq, WqT);

  // W2 = Weff @ Wq -> interleaved readout rows of W1
  w2_kernel<<<64, 512, 0, stream>>>(Weff, WqT, W1);

  // main fused GEMM -> out ; KV GEMM -> Yb
  gemm_main_kernel<<<1024, 512, 0, stream>>>(Xb, W1, hidden, out);
  gemm_kv_kernel<<<512, 512, 0, stream>>>(Xb, Wkv, Yb);

  // memory update
  mem_update_kernel<<<256, 256, 0, stream>>>(Yb, part);
  mem_reduce_kernel<<<256, 256, 0, stream>>>(part, memory, mem_out);
}